// Round 18
// baseline (905.247 us; speedup 1.0000x reference)
//
#include <hip/hip_runtime.h>
#include <math.h>

// Problem constants
#define N_B     2
#define T_SEQ   2048
#define D_MODEL 1024
#define N_HEADS 16
#define D_HEAD  64
#define TOPK_N  64
#define DCAP    64    // definite-in capacity (m <= 63 provably, EERR-independent)
#define ACAP    40    // ambiguous-band capacity (expected ~10)
#define QROWS   16    // q-rows per block (full MFMA B operand)
#define RPW     2     // q-rows per wave

// laplace(x) = 0.5*(1+erf((x-mu)*sqrt(2/pi))), mu=sqrt(.5)
#define LAP_MU_F  0.70710678f
#define LAP_INV_F 0.79788456f
// certified |s_bulk - s64| bound for K-hi-only MFMA scores (round-11-proven)
#define EERR      6e-3f

#define AS1 __attribute__((address_space(1)))
#define AS3 __attribute__((address_space(3)))

typedef _Float16 f16x4 __attribute__((ext_vector_type(4)));
typedef _Float16 f16x8 __attribute__((ext_vector_type(8)));
typedef float    f32x4 __attribute__((ext_vector_type(4)));
typedef double   f64x4 __attribute__((ext_vector_type(4)));

// decode monotone key back to float
__device__ __forceinline__ float key2f(unsigned k) {
  unsigned b = (k & 0x80000000u) ? (k & 0x7fffffffu) : ~k;
  return __uint_as_float(b);
}

// ---------------------------------------------------------------------------
// mask bit-pack: bits[row][lane] bit j = (mask[row][j*64+lane] != 0)
// ---------------------------------------------------------------------------
__global__ __launch_bounds__(256)
void pack_mask(const int* __restrict__ mask, unsigned* __restrict__ bits)
{
  const int wv = threadIdx.x >> 6, lane = threadIdx.x & 63;
  const int row = blockIdx.x * 4 + wv;             // 0 .. N_B*T_SEQ-1
  const int* mrow = mask + (size_t)row * T_SEQ;
  unsigned w = 0;
#pragma unroll
  for (int j = 0; j < 32; ++j)
    w |= (mrow[j * 64 + lane] != 0 ? 1u : 0u) << j;
  bits[(size_t)row * 64 + lane] = w;
}

// ---------------------------------------------------------------------------
// split16: f32 tensor [R][1024] -> f16 hi/lo images in GEMM LDS-chunk layout.
// ---------------------------------------------------------------------------
__global__ __launch_bounds__(256)
void split16(const float* __restrict__ src, char* __restrict__ dh,
             char* __restrict__ dl, float scale)
{
  const int tg = blockIdx.x * 256 + threadIdx.x;
  const int row = tg >> 7, unit = tg & 127;        // 128 8-col units per row
  const int c0 = unit * 8;
  const int rb = row >> 6, r = row & 63, kt = c0 >> 6, c = c0 & 63;
  const size_t off = (((size_t)rb * 16 + kt) << 13)
                   + (size_t)r * 128 + (size_t)((c * 2) ^ ((r & 7) << 4));
  float4 v0 = *reinterpret_cast<const float4*>(&src[(size_t)row * 1024 + c0]);
  float4 v1 = *reinterpret_cast<const float4*>(&src[(size_t)row * 1024 + c0 + 4]);
  f16x8 h, l;
  float x;
  x = v0.x * scale; h[0] = (_Float16)x; l[0] = (_Float16)(x - (float)h[0]);
  x = v0.y * scale; h[1] = (_Float16)x; l[1] = (_Float16)(x - (float)h[1]);
  x = v0.z * scale; h[2] = (_Float16)x; l[2] = (_Float16)(x - (float)h[2]);
  x = v0.w * scale; h[3] = (_Float16)x; l[3] = (_Float16)(x - (float)h[3]);
  x = v1.x * scale; h[4] = (_Float16)x; l[4] = (_Float16)(x - (float)h[4]);
  x = v1.y * scale; h[5] = (_Float16)x; l[5] = (_Float16)(x - (float)h[5]);
  x = v1.z * scale; h[6] = (_Float16)x; l[6] = (_Float16)(x - (float)h[6]);
  x = v1.w * scale; h[7] = (_Float16)x; l[7] = (_Float16)(x - (float)h[7]);
  *reinterpret_cast<f16x8*>(dh + off) = h;
  *reinterpret_cast<f16x8*>(dl + off) = l;
}

// ---------------------------------------------------------------------------
// f16-split MFMA GEMM from pre-split images (round-13..17-proven).
// ---------------------------------------------------------------------------
__global__ __launch_bounds__(256)
void gemm_mfma_f16i(const char* __restrict__ AhI, const char* __restrict__ AlI,
                    const char* __restrict__ BhI, const char* __restrict__ BlI,
                    const float* __restrict__ bias, float* __restrict__ out,
                    int N, int head_layout)
{
  __shared__ _Float16 LAh[4096], LAl[4096], LBh[4096], LBl[4096];   // 32 KB

  const int t = threadIdx.x, lane = t & 63, wv = t >> 6;
  const int row0 = blockIdx.x * 64, col0 = blockIdx.y * 64;
  const int wr = (wv >> 1) * 32, wc = (wv & 1) * 32;
  f32x4 acc[2][2] = {};

  for (int kt = 0; kt < 16; ++kt) {
    const size_t ca = (((size_t)blockIdx.x * 16 + kt) << 13);
    const size_t cb = (((size_t)blockIdx.y * 16 + kt) << 13);
#pragma unroll
    for (int j = 0; j < 2; ++j) {
      const int ub = wv * 64 + j * 256;            // wave-uniform 16B-unit base
      const size_t gu = (size_t)(ub + lane) * 16;
      __builtin_amdgcn_global_load_lds((const AS1 void*)(AhI + ca + gu),
                                       (AS3 void*)((char*)LAh + (size_t)ub * 16), 16, 0, 0);
      __builtin_amdgcn_global_load_lds((const AS1 void*)(AlI + ca + gu),
                                       (AS3 void*)((char*)LAl + (size_t)ub * 16), 16, 0, 0);
      __builtin_amdgcn_global_load_lds((const AS1 void*)(BhI + cb + gu),
                                       (AS3 void*)((char*)LBh + (size_t)ub * 16), 16, 0, 0);
      __builtin_amdgcn_global_load_lds((const AS1 void*)(BlI + cb + gu),
                                       (AS3 void*)((char*)LBl + (size_t)ub * 16), 16, 0, 0);
    }
    __syncthreads();

#pragma unroll
    for (int ks = 0; ks < 2; ++ks) {
      const int lg = ks * 64 + (lane >> 4) * 16;   // logical byte offset in row
      f16x8 a_h[2], a_l[2], b_h[2], b_l[2];
#pragma unroll
      for (int i = 0; i < 2; ++i) {
        int ar = wr + i * 16 + (lane & 15);
        int pa = ar * 128 + (lg ^ ((ar & 7) << 4));
        a_h[i] = *reinterpret_cast<const f16x8*>((const char*)LAh + pa);
        a_l[i] = *reinterpret_cast<const f16x8*>((const char*)LAl + pa);
        int bc = wc + i * 16 + (lane & 15);
        int pb = bc * 128 + (lg ^ ((bc & 7) << 4));
        b_h[i] = *reinterpret_cast<const f16x8*>((const char*)LBh + pb);
        b_l[i] = *reinterpret_cast<const f16x8*>((const char*)LBl + pb);
      }
#pragma unroll
      for (int i = 0; i < 2; ++i)
#pragma unroll
        for (int j = 0; j < 2; ++j) {
          acc[i][j] = __builtin_amdgcn_mfma_f32_16x16x32_f16(a_h[i], b_h[j], acc[i][j], 0, 0, 0);
          acc[i][j] = __builtin_amdgcn_mfma_f32_16x16x32_f16(a_l[i], b_h[j], acc[i][j], 0, 0, 0);
          acc[i][j] = __builtin_amdgcn_mfma_f32_16x16x32_f16(a_h[i], b_l[j], acc[i][j], 0, 0, 0);
        }
    }
    __syncthreads();
  }

#pragma unroll
  for (int i = 0; i < 2; ++i)
#pragma unroll
    for (int j = 0; j < 2; ++j)
#pragma unroll
      for (int r = 0; r < 4; ++r) {
        int row = row0 + wr + i * 16 + ((lane >> 4) & 3) * 4 + r;
        int col = col0 + wc + j * 16 + (lane & 15);
        float v = acc[i][j][r] * 0.015625f + bias[col];   // /64 (exact)
        if (head_layout) {
          int b = row >> 11, tt = row & (T_SEQ - 1);
          int hh = col >> 6, dk = col & 63;
          out[(((size_t)b * N_HEADS + hh) * T_SEQ + tt) * D_HEAD + dk] = v;
        } else {
          out[(size_t)row * N + col] = v;
        }
      }
}

// ---------------------------------------------------------------------------
// Merged f64 Q/K projection GEMM, self-verifying f64 MFMA, 64x128 tile.
// Round-18: LDS stages RAW f32 (convert on read — exact, bit-identical).
// Unlike round 12's regression, the f64 FLOPs are now on the MATRIX pipe
// (VALUBusy 12%), so the cvts land on an idle pipe; LDS 51.2 -> ~29.5 KB
// buys resident blocks to hide barrier drains.
// ---------------------------------------------------------------------------
__global__ __launch_bounds__(256)
void gemm_f64_qk(const float* __restrict__ Aq, const float* __restrict__ Ak,
                 const float* __restrict__ Wq, const float* __restrict__ Wk,
                 const float* __restrict__ bq, const float* __restrict__ bk,
                 double* __restrict__ Oq, double* __restrict__ Ok,
                 char* __restrict__ khS)
{
  __shared__ float As[64][33];      // 8.4 KB
  __shared__ float Ws[128][33];     // 16.9 KB
  __shared__ double redbuf[512];    // 4 KB (probe reduction)
  __shared__ double vals[2];
  __shared__ int okflag;

  const int z = blockIdx.z;
  const float* A    = z ? Ak : Aq;
  const float* W    = z ? Wk : Wq;
  const float* bias = z ? bk : bq;
  double* out       = z ? Ok : Oq;
  char* kh          = z ? khS : (char*)0;

  const int t = threadIdx.x, lane = t & 63, wv = t >> 6;
  const int row0 = blockIdx.x * 64, col0 = blockIdx.y * 128;
  const int wr = (wv >> 1) * 32, wc = (wv & 1) * 64;
  f64x4 acc[2][4] = {};

  for (int k0 = 0; k0 < D_MODEL; k0 += 32) {
#pragma unroll
    for (int jj = 0; jj < 2; ++jj) {
      int idx = t + jj * 256;                 // 0..511: A tile (64 x 8 float4)
      int r = idx >> 3, kq = idx & 7;
      float4 va = *reinterpret_cast<const float4*>(&A[(size_t)(row0 + r) * D_MODEL + k0 + kq * 4]);
      As[r][kq*4+0] = va.x; As[r][kq*4+1] = va.y;
      As[r][kq*4+2] = va.z; As[r][kq*4+3] = va.w;
    }
#pragma unroll
    for (int jj = 0; jj < 4; ++jj) {
      int idx = t + jj * 256;                 // 0..1023: W tile (128 x 8 float4)
      int r = idx >> 3, kq = idx & 7;
      float4 vw = *reinterpret_cast<const float4*>(&W[(size_t)(col0 + r) * D_MODEL + k0 + kq * 4]);
      Ws[r][kq*4+0] = vw.x; Ws[r][kq*4+1] = vw.y;
      Ws[r][kq*4+2] = vw.z; Ws[r][kq*4+3] = vw.w;
    }
    __syncthreads();
#pragma unroll
    for (int kk = 0; kk < 32; kk += 4) {
      const int kf = kk + (lane >> 4);
      double a0 = (double)As[wr +      (lane & 15)][kf];
      double a1 = (double)As[wr + 16 + (lane & 15)][kf];
      double b0 = (double)Ws[wc +      (lane & 15)][kf];
      double b1 = (double)Ws[wc + 16 + (lane & 15)][kf];
      double b2 = (double)Ws[wc + 32 + (lane & 15)][kf];
      double b3 = (double)Ws[wc + 48 + (lane & 15)][kf];
      acc[0][0] = __builtin_amdgcn_mfma_f64_16x16x4f64(a0, b0, acc[0][0], 0, 0, 0);
      acc[0][1] = __builtin_amdgcn_mfma_f64_16x16x4f64(a0, b1, acc[0][1], 0, 0, 0);
      acc[0][2] = __builtin_amdgcn_mfma_f64_16x16x4f64(a0, b2, acc[0][2], 0, 0, 0);
      acc[0][3] = __builtin_amdgcn_mfma_f64_16x16x4f64(a0, b3, acc[0][3], 0, 0, 0);
      acc[1][0] = __builtin_amdgcn_mfma_f64_16x16x4f64(a1, b0, acc[1][0], 0, 0, 0);
      acc[1][1] = __builtin_amdgcn_mfma_f64_16x16x4f64(a1, b1, acc[1][1], 0, 0, 0);
      acc[1][2] = __builtin_amdgcn_mfma_f64_16x16x4f64(a1, b2, acc[1][2], 0, 0, 0);
      acc[1][3] = __builtin_amdgcn_mfma_f64_16x16x4f64(a1, b3, acc[1][3], 0, 0, 0);
    }
    __syncthreads();
  }

  // ---- probe: verify D[6][5] (t=37, acc[0][0][1]) and D[13][3] (t=19, acc[0][0][3])
  if (t == 37) vals[0] = acc[0][0][1];
  if (t == 19) vals[1] = acc[0][0][3];
  {
    double p1 = 0, p2 = 0;
    const int kb = t * 4;
#pragma unroll
    for (int k = 0; k < 4; ++k) {
      p1 = fma((double)A[(size_t)(row0 + 6) * D_MODEL + kb + k],
               (double)W[(size_t)(col0 + 5) * D_MODEL + kb + k], p1);
      p2 = fma((double)A[(size_t)(row0 + 13) * D_MODEL + kb + k],
               (double)W[(size_t)(col0 + 3) * D_MODEL + kb + k], p2);
    }
    redbuf[t] = p1; redbuf[256 + t] = p2;
  }
  __syncthreads();
  for (int s = 128; s > 0; s >>= 1) {
    if (t < s) { redbuf[t] += redbuf[t + s]; redbuf[256 + t] += redbuf[256 + t + s]; }
    __syncthreads();
  }
  if (t == 0) {
    double r1 = redbuf[0], r2 = redbuf[256];
    bool ok = (fabs(r1 - vals[0]) <= 1e-9 * (fabs(r1) + 1.0)) &&
              (fabs(r2 - vals[1]) <= 1e-9 * (fabs(r2) + 1.0));
    okflag = ok ? 1 : 0;
  }
  __syncthreads();

  if (okflag) {
#pragma unroll
    for (int i = 0; i < 2; ++i)
#pragma unroll
      for (int j = 0; j < 4; ++j)
#pragma unroll
        for (int r = 0; r < 4; ++r) {
          int row = row0 + wr + i * 16 + (lane >> 4) + 4 * r;
          int col = col0 + wc + j * 16 + (lane & 15);
          double v = acc[i][j][r] + (double)bias[col];
          int b = row >> 11, tt = row & (T_SEQ - 1);
          int h = col >> 6, dk = col & 63;
          size_t oi = (((size_t)b * N_HEADS + h) * T_SEQ + tt) * D_HEAD + dk;
          out[oi] = v;
          if (kh) {
            _Float16 hh = (_Float16)(float)v;
            int cch = tt >> 7, klo = tt & 127;
            size_t off = (((size_t)(b * N_HEADS + h) * 16 + cch) << 14)
                       + (size_t)klo * 128 + (size_t)((dk * 2) ^ ((klo & 7) << 4));
            *reinterpret_cast<_Float16*>(kh + off) = hh;
          }
        }
  } else {
    // VALU fallback: 64x128 staged path (f32 stage, cvt on read — same values)
    const int ty = t >> 4, tx = t & 15;
    double vacc[4][8] = {{0.0}};
    for (int k0 = 0; k0 < D_MODEL; k0 += 32) {
#pragma unroll
      for (int jj = 0; jj < 2; ++jj) {
        int idx = t + jj * 256;
        int r = idx >> 3, kq = idx & 7;
        float4 va = *reinterpret_cast<const float4*>(&A[(size_t)(row0 + r) * D_MODEL + k0 + kq * 4]);
        As[r][kq*4+0] = va.x; As[r][kq*4+1] = va.y;
        As[r][kq*4+2] = va.z; As[r][kq*4+3] = va.w;
      }
#pragma unroll
      for (int jj = 0; jj < 4; ++jj) {
        int idx = t + jj * 256;
        int r = idx >> 3, kq = idx & 7;
        float4 vw = *reinterpret_cast<const float4*>(&W[(size_t)(col0 + r) * D_MODEL + k0 + kq * 4]);
        Ws[r][kq*4+0] = vw.x; Ws[r][kq*4+1] = vw.y;
        Ws[r][kq*4+2] = vw.z; Ws[r][kq*4+3] = vw.w;
      }
      __syncthreads();
#pragma unroll
      for (int kk = 0; kk < 32; ++kk) {
        double a[4], b[8];
#pragma unroll
        for (int i = 0; i < 4; ++i) a[i] = (double)As[ty + 16*i][kk];
#pragma unroll
        for (int j = 0; j < 8; ++j) b[j] = (double)Ws[tx + 16*j][kk];
#pragma unroll
        for (int i = 0; i < 4; ++i)
#pragma unroll
          for (int j = 0; j < 8; ++j) vacc[i][j] = fma(a[i], b[j], vacc[i][j]);
      }
      __syncthreads();
    }
#pragma unroll
    for (int i = 0; i < 4; ++i)
#pragma unroll
      for (int j = 0; j < 8; ++j) {
        int row = row0 + ty + 16*i, col = col0 + tx + 16*j;
        double v = vacc[i][j] + (double)bias[col];
        int b = row >> 11, tt = row & (T_SEQ - 1);
        int h = col >> 6, dk = col & 63;
        size_t oi = (((size_t)b * N_HEADS + h) * T_SEQ + tt) * D_HEAD + dk;
        out[oi] = v;
        if (kh) {
          _Float16 hh = (_Float16)(float)v;
          int cch = tt >> 7, klo = tt & 127;
          size_t off = (((size_t)(b * N_HEADS + h) * 16 + cch) << 14)
                     + (size_t)klo * 128 + (size_t)((dk * 2) ^ ((klo & 7) << 4));
          *reinterpret_cast<_Float16*>(kh + off) = hh;
        }
      }
  }
}

// ---------------------------------------------------------------------------
// Per-row tail with certified bands (round-16-proven).
// ---------------------------------------------------------------------------
__device__ __forceinline__ void process_row(
    const float (&s)[32], int* __restrict__ dkl, float* __restrict__ dwl,
    int* __restrict__ akl, float* __restrict__ awl,
    const double* __restrict__ qrow, const double* __restrict__ Kd,
    const float* __restrict__ V, unsigned mw,
    char* __restrict__ axh, char* __restrict__ axl,
    size_t axbase, int rsw, size_t kvbase, int lane)
{
  // fp32 64th-largest to 16384-ulp resolution (quant ~2e-3, folded into band)
  unsigned p = 0u;
  for (int bit = 31; bit >= 14; --bit) {
    unsigned cand = p | (1u << bit);
    float cf = key2f(cand);
    int cnt = 0;
#pragma unroll
    for (int j = 0; j < 32; ++j) cnt += (int)__popcll(__ballot(s[j] >= cf));
    if (cnt >= TOPK_N) p = cand;
  }
  const float pv = key2f(p);            // pv <= v32
  const float pn = key2f(p + 16384u);   // v32 < pn
  const float hi = pn + 2.f * EERR;     // s>=hi  => certainly in f64 top-64
  const float lo = pv - 2.f * EERR;     // s<lo   => certainly out

  // compact definite list (raw scores) and ambiguous list
  int m = 0, na = 0;
#pragma unroll
  for (int j = 0; j < 32; ++j) {
    float sv = s[j];
    bool isd = (sv >= hi);
    bool isa = (sv >= lo) && !isd;
    unsigned long long bd = __ballot(isd);
    unsigned long long ba = __ballot(isa);
    int k = j * 64 + lane;
    if (isd) {
      int pos = m + (int)__popcll(bd & ((1ull << lane) - 1ull));
      if (pos < DCAP) { dkl[pos] = k; dwl[pos] = sv; }
    }
    if (isa) {
      int pos = na + (int)__popcll(ba & ((1ull << lane) - 1ull));
      if (pos < ACAP) akl[pos] = k;
    }
    m += (int)__popcll(bd);
    na += (int)__popcll(ba);
  }
  if (m > DCAP) m = DCAP;   // unreachable: m <= 63
  if (na > ACAP) na = ACAP;
  const int need = TOPK_N - m;

  // deferred mask+laplace for definite list: one erf for all lanes
  {
    int kdef = dkl[lane];               // lane>=m reads stale LDS (safe)
    float sdef = dwl[lane];
    unsigned mwd = __shfl(mw, kdef & 63);
    bool mskd = ((mwd >> (kdef >> 6)) & 1u) != 0u;
    float wdef = mskd ? 0.f : 0.5f * (1.f + erff((sdef - LAP_MU_F) * LAP_INV_F));
    if (lane < m) dwl[lane] = wdef;
  }

  // lane-parallel f64 refine of ambiguous candidates (lane e owns akl[e])
  int ke = (na > 0) ? akl[lane < na ? lane : 0] : 0;
  const double* kr = &Kd[kvbase + (size_t)ke * D_HEAD];
  double a0 = 0, a1 = 0, a2 = 0, a3 = 0;
#pragma unroll
  for (int d = 0; d < 64; d += 4) {
    a0 = fma(qrow[d + 0], kr[d + 0], a0);
    a1 = fma(qrow[d + 1], kr[d + 1], a1);
    a2 = fma(qrow[d + 2], kr[d + 2], a2);
    a3 = fma(qrow[d + 3], kr[d + 3], a3);
  }
  double s64e = ((a0 + a1) + (a2 + a3)) * 0.125;

  // mask bit for own ambiguous candidate (cross-lane word fetch)
  unsigned mwk = __shfl(mw, ke & 63);
  bool mska = ((mwk >> (ke >> 6)) & 1u) != 0u;

  // rank among A by exact f64 (strict >): rank<need <=> s64 >= vk (ties kept)
  int rank = 0;
  for (int i = 0; i < na; ++i) {
    double vi = __shfl(s64e, i);
    rank += (vi > s64e) ? 1 : 0;
  }
  if (lane < na) {
    bool keep = (rank < need) && !mska;
    awl[lane] = keep ? 0.5f * (1.f + erff(((float)s64e - LAP_MU_F) * LAP_INV_F)) : 0.f;
  }

  // PV: lane owns output dim d=lane; 4 accumulators -> 4 outstanding loads
  float c0 = 0.f, c1 = 0.f, c2 = 0.f, c3 = 0.f;
  int e = 0;
  for (; e + 4 <= m; e += 4) {
    c0 = fmaf(dwl[e+0], V[kvbase + (size_t)dkl[e+0] * D_HEAD + lane], c0);
    c1 = fmaf(dwl[e+1], V[kvbase + (size_t)dkl[e+1] * D_HEAD + lane], c1);
    c2 = fmaf(dwl[e+2], V[kvbase + (size_t)dkl[e+2] * D_HEAD + lane], c2);
    c3 = fmaf(dwl[e+3], V[kvbase + (size_t)dkl[e+3] * D_HEAD + lane], c3);
  }
  for (; e < m; ++e)
    c0 = fmaf(dwl[e], V[kvbase + (size_t)dkl[e] * D_HEAD + lane], c0);
  for (int e2 = 0; e2 < na; ++e2)
    c1 = fmaf(awl[e2], V[kvbase + (size_t)akl[e2] * D_HEAD + lane], c1);

  float val = (c0 + c1) + (c2 + c3);
  _Float16 vh = (_Float16)val;
  _Float16 vl = (_Float16)(val - (float)vh);
  size_t off = axbase + (size_t)((lane * 2) ^ rsw);
  *reinterpret_cast<_Float16*>(axh + off) = vh;
  *reinterpret_cast<_Float16*>(axl + off) = vl;
}

// ---------------------------------------------------------------------------
// Fused attention (round-16/17-proven): direct-to-register K from the
// pre-swizzled image, 1-chunk prefetch, S_lds dbuf transpose, image output.
// ---------------------------------------------------------------------------
__global__ __launch_bounds__(512)
void attn_fused(const double* __restrict__ Qd, const double* __restrict__ Kd,
                const char* __restrict__ KhS, const float* __restrict__ V,
                const unsigned* __restrict__ mbits,
                char* __restrict__ AxH, char* __restrict__ AxL)
{
  __shared__ float    S_lds[2][128][17];  // 17 KB double-buffered transpose
  __shared__ char     pool[8192];         // QhL/QlL (prologue) | dk_l/dw_l (tail)
  __shared__ int      ak_l[QROWS][ACAP];  // 2.5 KB
  __shared__ float    aw_l[QROWS][ACAP];  // 2.5 KB

  _Float16 (*QhL)[64] = reinterpret_cast<_Float16(*)[64]>(pool);          // [16][64] 2KB
  _Float16 (*QlL)[64] = reinterpret_cast<_Float16(*)[64]>(pool + 2048);   // [16][64] 2KB
  int      (*dk_l)[DCAP] = reinterpret_cast<int(*)[DCAP]>(pool);          // [16][64] 4KB
  float    (*dw_l)[DCAP] = reinterpret_cast<float(*)[DCAP]>(pool + 4096); // [16][64] 4KB

  const int t = threadIdx.x, wv = t >> 6, lane = t & 63;
  const int bh = blockIdx.y, b = bh >> 4, h = bh & 15;
  const int q0 = blockIdx.x * QROWS;
  const size_t kvbase = (size_t)bh * T_SEQ * D_HEAD;
  const char* gbase = KhS + (((size_t)bh * 16) << 14);   // this bh's chunks

  // prologue: stage q rows (f16 hi/lo for MFMA B)
  for (int i = t; i < QROWS * 64; i += 512) {
    int r = i >> 6, d = i & 63;
    float qf = (float)Qd[kvbase + (size_t)(q0 + r) * D_HEAD + d];
    _Float16 hh = (_Float16)qf;
    QhL[r][d] = hh;
    QlL[r][d] = (_Float16)(qf - (float)hh);
  }
  __syncthreads();

  // hoist Q fragments: col=lane&15 (all 16 live), k=(lane>>4)*8+j
  const int qcol = lane & 15;
  const int kq = (lane >> 4) * 8;
  f16x8 Bh[2], Bl[2];
#pragma unroll
  for (int ds_ = 0; ds_ < 2; ++ds_) {
    Bh[ds_] = *reinterpret_cast<const f16x8*>(&QhL[qcol][ds_ * 32 + kq]);
    Bl[ds_] = *reinterpret_cast<const f16x8*>(&QlL[qcol][ds_ * 32 + kq]);
  }

  // per-lane K-image offsets within a chunk (wave's own 16 rows)
  const int rloc = wv * 16 + (lane & 15);
  const int off0 = rloc * 128 + ((0 * 64 + (lane >> 4) * 16) ^ ((rloc & 7) << 4));
  const int off1 = rloc * 128 + ((1 * 64 + (lane >> 4) * 16) ^ ((rloc & 7) << 4));

  const int r0 = wv * RPW;
  float s0[32], s1[32];

  // prefetch chunk 0
  f16x8 a0c = *reinterpret_cast<const f16x8*>(gbase + off0);
  f16x8 a1c = *reinterpret_cast<const f16x8*>(gbase + off1);

#pragma unroll
  for (int c = 0; c < 16; ++c) {
    const int cur = c & 1;
    // issue next chunk's loads (latency hides under MFMA + barrier)
    f16x8 a0n, a1n;
    if (c < 15) {
      const char* gc = gbase + ((size_t)(c + 1) << 14);
      a0n = *reinterpret_cast<const f16x8*>(gc + off0);
      a1n = *reinterpret_cast<const f16x8*>(gc + off1);
    }

    // MFMA: wave covers its 16 k-rows of chunk c
    f32x4 acc = {0.f, 0.f, 0.f, 0.f};
    acc = __builtin_amdgcn_mfma_f32_16x16x32_f16(a0c, Bh[0], acc, 0, 0, 0);
    acc = __builtin_amdgcn_mfma_f32_16x16x32_f16(a0c, Bl[0], acc, 0, 0, 0);
    acc = __builtin_amdgcn_mfma_f32_16x16x32_f16(a1c, Bh[1], acc, 0, 0, 0);
    acc = __builtin_amdgcn_mfma_f32_16x16x32_f16(a1c, Bl[1], acc, 0, 0, 0);

    // scatter D: row = k-local = wv*16 + (lane>>4)*4 + r2, col = q
#pragma unroll
    for (int r2 = 0; r2 < 4; ++r2)
      S_lds[cur][wv * 16 + (lane >> 4) * 4 + r2][qcol] = acc[r2];

    __syncthreads();   // orders scatter vs gather (dbuf parity protects reuse)

    // gather into selection layout: s[j] = score[k = j*64+lane]
    s0[c * 2 + 0] = S_lds[cur][lane][r0]          * 0.125f;
    s0[c * 2 + 1] = S_lds[cur][64 + lane][r0]     * 0.125f;
    s1[c * 2 + 0] = S_lds[cur][lane][r0 + 1]      * 0.125f;
    s1[c * 2 + 1] = S_lds[cur][64 + lane][r0 + 1] * 0.125f;

    a0c = a0n; a1c = a1n;
  }

  // wave-private tails (pool now reused as dk_l/dw_l — Q reads long done)
  {
    const int lr = r0, qg = q0 + lr;
    const size_t rowg = (size_t)b * T_SEQ + qg;
    unsigned mw = mbits[rowg * 64 + lane];
    int rb = (int)(rowg >> 6), rr = (int)(rowg & 63);
    size_t axbase = (((size_t)rb * 16 + h) << 13) + (size_t)rr * 128;
    process_row(s0, dk_l[lr], dw_l[lr], ak_l[lr], aw_l[lr],
                &Qd[kvbase + (size_t)qg * D_HEAD], Kd, V, mw,
                AxH, AxL, axbase, (rr & 7) << 4, kvbase, lane);
  }
  {
    const int lr = r0 + 1, qg = q0 + lr;
    const size_t rowg = (size_t)b * T_SEQ + qg;
    unsigned mw = mbits[rowg * 64 + lane];
    int rb = (int)(rowg >> 6), rr = (int)(rowg & 63);
    size_t axbase = (((size_t)rb * 16 + h) << 13) + (size_t)rr * 128;
    process_row(s1, dk_l[lr], dw_l[lr], ak_l[lr], aw_l[lr],
                &Qd[kvbase + (size_t)qg * D_HEAD], Kd, V, mw,
                AxH, AxL, axbase, (rr & 7) << 4, kvbase, lane);
  }
}

// ---------------------------------------------------------------------------
extern "C" void kernel_launch(void* const* d_in, const int* in_sizes, int n_in,
                              void* d_out, int out_size, void* d_ws, size_t ws_size,
                              hipStream_t stream)
{
  const float* query = (const float*)d_in[0];
  const float* key_  = (const float*)d_in[1];
  const float* value = (const float*)d_in[2];
  const int*   mask  = (const int*)d_in[3];
  const float* wq = (const float*)d_in[4];
  const float* bq = (const float*)d_in[5];
  const float* wk = (const float*)d_in[6];
  const float* bk = (const float*)d_in[7];
  const float* wvp = (const float*)d_in[8];
  const float* bv = (const float*)d_in[9];
  const float* wo = (const float*)d_in[10];
  const float* bo = (const float*)d_in[11];
  float* out = (float*)d_out;

  // ws regions (97 MB):
  //   [0,32M)   Qd f64     — transiently BvH/BvL images before Q-GEMM
  //   [32,64M)  Kd f64     — transiently AvH/AvL images; BoH/BoL after attn
  //   [64,72M)  KhS
  //   [80,96M)  AxH/AxL (attn output images, 8M each)
  //   [96,97M)  mbits
  double* Qd  = (double*)d_ws;
  double* Kd  = (double*)((char*)d_ws + ((size_t)32 << 20));
  char*   KhS = (char*)d_ws + ((size_t)64 << 20);
  char*   AxH = (char*)d_ws + ((size_t)80 << 20);
  char*   AxL = (char*)d_ws + ((size_t)88 << 20);
  unsigned* mbits = (unsigned*)((char*)d_ws + ((size_t)96 << 20));
  float*  Vb  = out;   // V-projection parks in d_out; final GEMM overwrites it

  char* BvH = (char*)d_ws;                                   // 2 MB  (wv hi)
  char* BvL = (char*)d_ws + ((size_t)2 << 20);               // 2 MB  (wv lo)
  char* AvH = (char*)d_ws + ((size_t)32 << 20);              // 8 MB  (value hi)
  char* AvL = (char*)d_ws + ((size_t)40 << 20);              // 8 MB  (value lo)
  char* BoH = (char*)d_ws + ((size_t)32 << 20);              // 2 MB  (wo hi, post-attn)
  char* BoL = (char*)d_ws + ((size_t)34 << 20);              // 2 MB  (wo lo)

  const int M = N_B * T_SEQ;   // 4096
  dim3 gg64(M / 64, D_MODEL / 64);

  // 1) V path first: its images live in the not-yet-written Qd/Kd regions
  hipLaunchKernelGGL(split16, dim3(1024 * 128 / 256), dim3(256), 0, stream, wvp, BvH, BvL, 64.f);
  hipLaunchKernelGGL(split16, dim3((size_t)M * 128 / 256), dim3(256), 0, stream, value, AvH, AvL, 1.f);
  hipLaunchKernelGGL(gemm_mfma_f16i, gg64, dim3(256), 0, stream, AvH, AvL, BvH, BvL,
                     bv, Vb, D_MODEL, 1);

  // 2) mask pack + merged f64 Q/K projection (self-verifying MFMA, 64x128 tile)
  hipLaunchKernelGGL(pack_mask, dim3(M / 4), dim3(256), 0, stream, mask, mbits);
  dim3 gqk(M / 64, D_MODEL / 128, 2);
  hipLaunchKernelGGL(gemm_f64_qk, gqk, dim3(256), 0, stream,
                     query, key_, wq, wk, bq, bk, Qd, Kd, KhS);

  // 3) fused attention (writes AxH/AxL images directly)
  dim3 ga(T_SEQ / QROWS, N_B * N_HEADS);
  hipLaunchKernelGGL(attn_fused, ga, dim3(512), 0, stream, Qd, Kd, KhS, Vb, mbits, AxH, AxL);

  // 4) O path: wo images reuse Kd region (dead after attn)
  hipLaunchKernelGGL(split16, dim3(1024 * 128 / 256), dim3(256), 0, stream, wo, BoH, BoL, 64.f);
  hipLaunchKernelGGL(gemm_mfma_f16i, gg64, dim3(256), 0, stream, AxH, AxL, BoH, BoL,
                     bo, out, D_MODEL, 0);
}

// Round 19
// 847.829 us; speedup vs baseline: 1.0677x; 1.0677x over previous
//
#include <hip/hip_runtime.h>
#include <math.h>

// Problem constants
#define N_B     2
#define T_SEQ   2048
#define D_MODEL 1024
#define N_HEADS 16
#define D_HEAD  64
#define TOPK_N  64
#define DCAP    64    // definite-in capacity (m <= 63 provably, EERR-independent)
#define ACAP    40    // ambiguous-band capacity (expected ~10)
#define QROWS   16    // q-rows per block (full MFMA B operand)
#define RPW     2     // q-rows per wave

// laplace(x) = 0.5*(1+erf((x-mu)*sqrt(2/pi))), mu=sqrt(.5)
#define LAP_MU_F  0.70710678f
#define LAP_INV_F 0.79788456f
// certified |s_bulk - s64| bound for K-hi-only MFMA scores (round-11-proven)
#define EERR      6e-3f

#define AS1 __attribute__((address_space(1)))
#define AS3 __attribute__((address_space(3)))

typedef _Float16 f16x4 __attribute__((ext_vector_type(4)));
typedef _Float16 f16x8 __attribute__((ext_vector_type(8)));
typedef float    f32x4 __attribute__((ext_vector_type(4)));
typedef double   f64x4 __attribute__((ext_vector_type(4)));

// decode monotone key back to float
__device__ __forceinline__ float key2f(unsigned k) {
  unsigned b = (k & 0x80000000u) ? (k & 0x7fffffffu) : ~k;
  return __uint_as_float(b);
}

// ---------------------------------------------------------------------------
// mask bit-pack: bits[row][lane] bit j = (mask[row][j*64+lane] != 0)
// ---------------------------------------------------------------------------
__global__ __launch_bounds__(256)
void pack_mask(const int* __restrict__ mask, unsigned* __restrict__ bits)
{
  const int wv = threadIdx.x >> 6, lane = threadIdx.x & 63;
  const int row = blockIdx.x * 4 + wv;             // 0 .. N_B*T_SEQ-1
  const int* mrow = mask + (size_t)row * T_SEQ;
  unsigned w = 0;
#pragma unroll
  for (int j = 0; j < 32; ++j)
    w |= (mrow[j * 64 + lane] != 0 ? 1u : 0u) << j;
  bits[(size_t)row * 64 + lane] = w;
}

// ---------------------------------------------------------------------------
// split16: f32 tensor [R][1024] -> f16 hi/lo images in GEMM LDS-chunk layout.
// ---------------------------------------------------------------------------
__global__ __launch_bounds__(256)
void split16(const float* __restrict__ src, char* __restrict__ dh,
             char* __restrict__ dl, float scale)
{
  const int tg = blockIdx.x * 256 + threadIdx.x;
  const int row = tg >> 7, unit = tg & 127;        // 128 8-col units per row
  const int c0 = unit * 8;
  const int rb = row >> 6, r = row & 63, kt = c0 >> 6, c = c0 & 63;
  const size_t off = (((size_t)rb * 16 + kt) << 13)
                   + (size_t)r * 128 + (size_t)((c * 2) ^ ((r & 7) << 4));
  float4 v0 = *reinterpret_cast<const float4*>(&src[(size_t)row * 1024 + c0]);
  float4 v1 = *reinterpret_cast<const float4*>(&src[(size_t)row * 1024 + c0 + 4]);
  f16x8 h, l;
  float x;
  x = v0.x * scale; h[0] = (_Float16)x; l[0] = (_Float16)(x - (float)h[0]);
  x = v0.y * scale; h[1] = (_Float16)x; l[1] = (_Float16)(x - (float)h[1]);
  x = v0.z * scale; h[2] = (_Float16)x; l[2] = (_Float16)(x - (float)h[2]);
  x = v0.w * scale; h[3] = (_Float16)x; l[3] = (_Float16)(x - (float)h[3]);
  x = v1.x * scale; h[4] = (_Float16)x; l[4] = (_Float16)(x - (float)h[4]);
  x = v1.y * scale; h[5] = (_Float16)x; l[5] = (_Float16)(x - (float)h[5]);
  x = v1.z * scale; h[6] = (_Float16)x; l[6] = (_Float16)(x - (float)h[6]);
  x = v1.w * scale; h[7] = (_Float16)x; l[7] = (_Float16)(x - (float)h[7]);
  *reinterpret_cast<f16x8*>(dh + off) = h;
  *reinterpret_cast<f16x8*>(dl + off) = l;
}

// ---------------------------------------------------------------------------
// f16-split MFMA GEMM from pre-split images (round-13..18-proven).
// ---------------------------------------------------------------------------
__global__ __launch_bounds__(256)
void gemm_mfma_f16i(const char* __restrict__ AhI, const char* __restrict__ AlI,
                    const char* __restrict__ BhI, const char* __restrict__ BlI,
                    const float* __restrict__ bias, float* __restrict__ out,
                    int N, int head_layout)
{
  __shared__ _Float16 LAh[4096], LAl[4096], LBh[4096], LBl[4096];   // 32 KB

  const int t = threadIdx.x, lane = t & 63, wv = t >> 6;
  const int row0 = blockIdx.x * 64, col0 = blockIdx.y * 64;
  const int wr = (wv >> 1) * 32, wc = (wv & 1) * 32;
  f32x4 acc[2][2] = {};

  for (int kt = 0; kt < 16; ++kt) {
    const size_t ca = (((size_t)blockIdx.x * 16 + kt) << 13);
    const size_t cb = (((size_t)blockIdx.y * 16 + kt) << 13);
#pragma unroll
    for (int j = 0; j < 2; ++j) {
      const int ub = wv * 64 + j * 256;            // wave-uniform 16B-unit base
      const size_t gu = (size_t)(ub + lane) * 16;
      __builtin_amdgcn_global_load_lds((const AS1 void*)(AhI + ca + gu),
                                       (AS3 void*)((char*)LAh + (size_t)ub * 16), 16, 0, 0);
      __builtin_amdgcn_global_load_lds((const AS1 void*)(AlI + ca + gu),
                                       (AS3 void*)((char*)LAl + (size_t)ub * 16), 16, 0, 0);
      __builtin_amdgcn_global_load_lds((const AS1 void*)(BhI + cb + gu),
                                       (AS3 void*)((char*)LBh + (size_t)ub * 16), 16, 0, 0);
      __builtin_amdgcn_global_load_lds((const AS1 void*)(BlI + cb + gu),
                                       (AS3 void*)((char*)LBl + (size_t)ub * 16), 16, 0, 0);
    }
    __syncthreads();

#pragma unroll
    for (int ks = 0; ks < 2; ++ks) {
      const int lg = ks * 64 + (lane >> 4) * 16;   // logical byte offset in row
      f16x8 a_h[2], a_l[2], b_h[2], b_l[2];
#pragma unroll
      for (int i = 0; i < 2; ++i) {
        int ar = wr + i * 16 + (lane & 15);
        int pa = ar * 128 + (lg ^ ((ar & 7) << 4));
        a_h[i] = *reinterpret_cast<const f16x8*>((const char*)LAh + pa);
        a_l[i] = *reinterpret_cast<const f16x8*>((const char*)LAl + pa);
        int bc = wc + i * 16 + (lane & 15);
        int pb = bc * 128 + (lg ^ ((bc & 7) << 4));
        b_h[i] = *reinterpret_cast<const f16x8*>((const char*)LBh + pb);
        b_l[i] = *reinterpret_cast<const f16x8*>((const char*)LBl + pb);
      }
#pragma unroll
      for (int i = 0; i < 2; ++i)
#pragma unroll
        for (int j = 0; j < 2; ++j) {
          acc[i][j] = __builtin_amdgcn_mfma_f32_16x16x32_f16(a_h[i], b_h[j], acc[i][j], 0, 0, 0);
          acc[i][j] = __builtin_amdgcn_mfma_f32_16x16x32_f16(a_l[i], b_h[j], acc[i][j], 0, 0, 0);
          acc[i][j] = __builtin_amdgcn_mfma_f32_16x16x32_f16(a_h[i], b_l[j], acc[i][j], 0, 0, 0);
        }
    }
    __syncthreads();
  }

#pragma unroll
  for (int i = 0; i < 2; ++i)
#pragma unroll
    for (int j = 0; j < 2; ++j)
#pragma unroll
      for (int r = 0; r < 4; ++r) {
        int row = row0 + wr + i * 16 + ((lane >> 4) & 3) * 4 + r;
        int col = col0 + wc + j * 16 + (lane & 15);
        float v = acc[i][j][r] * 0.015625f + bias[col];   // /64 (exact)
        if (head_layout) {
          int b = row >> 11, tt = row & (T_SEQ - 1);
          int hh = col >> 6, dk = col & 63;
          out[(((size_t)b * N_HEADS + hh) * T_SEQ + tt) * D_HEAD + dk] = v;
        } else {
          out[(size_t)row * N + col] = v;
        }
      }
}

// ---------------------------------------------------------------------------
// Merged f64 Q/K projection GEMM, self-verifying f64 MFMA, 64x128 tile,
// f32 staging (cvt-on-read, exact). Round-19: T14 issue-early/write-late
// pipeline — regs hold tile c+1's global loads, issued right after the
// write-phase barrier so they fly during the MFMA phase. Same barriers,
// bit-identical values.
// ---------------------------------------------------------------------------
__global__ __launch_bounds__(256)
void gemm_f64_qk(const float* __restrict__ Aq, const float* __restrict__ Ak,
                 const float* __restrict__ Wq, const float* __restrict__ Wk,
                 const float* __restrict__ bq, const float* __restrict__ bk,
                 double* __restrict__ Oq, double* __restrict__ Ok,
                 char* __restrict__ khS)
{
  __shared__ float As[64][33];      // 8.4 KB
  __shared__ float Ws[128][33];     // 16.9 KB
  __shared__ double redbuf[512];    // 4 KB (probe reduction)
  __shared__ double vals[2];
  __shared__ int okflag;

  const int z = blockIdx.z;
  const float* A    = z ? Ak : Aq;
  const float* W    = z ? Wk : Wq;
  const float* bias = z ? bk : bq;
  double* out       = z ? Ok : Oq;
  char* kh          = z ? khS : (char*)0;

  const int t = threadIdx.x, lane = t & 63, wv = t >> 6;
  const int row0 = blockIdx.x * 64, col0 = blockIdx.y * 128;
  const int wr = (wv >> 1) * 32, wc = (wv & 1) * 64;
  f64x4 acc[2][4] = {};

  // per-thread staging coordinates (fixed across tiles)
  const int ar_ = t >> 3, akq_ = t & 7;            // A: rows 0..63 via t, +256 -> +32 rows
  float4 ra[2], rw[4];

  // prologue: global loads for tile k0=0
#pragma unroll
  for (int jj = 0; jj < 2; ++jj) {
    int idx = t + jj * 256, r = idx >> 3, kq = idx & 7;
    ra[jj] = *reinterpret_cast<const float4*>(&A[(size_t)(row0 + r) * D_MODEL + kq * 4]);
  }
#pragma unroll
  for (int jj = 0; jj < 4; ++jj) {
    int idx = t + jj * 256, r = idx >> 3, kq = idx & 7;
    rw[jj] = *reinterpret_cast<const float4*>(&W[(size_t)(col0 + r) * D_MODEL + kq * 4]);
  }

  for (int k0 = 0; k0 < D_MODEL; k0 += 32) {
    // ---- write staged regs to LDS ----
#pragma unroll
    for (int jj = 0; jj < 2; ++jj) {
      int idx = t + jj * 256, r = idx >> 3, kq = idx & 7;
      As[r][kq*4+0] = ra[jj].x; As[r][kq*4+1] = ra[jj].y;
      As[r][kq*4+2] = ra[jj].z; As[r][kq*4+3] = ra[jj].w;
    }
#pragma unroll
    for (int jj = 0; jj < 4; ++jj) {
      int idx = t + jj * 256, r = idx >> 3, kq = idx & 7;
      Ws[r][kq*4+0] = rw[jj].x; Ws[r][kq*4+1] = rw[jj].y;
      Ws[r][kq*4+2] = rw[jj].z; Ws[r][kq*4+3] = rw[jj].w;
    }
    __syncthreads();

    // ---- issue NEXT tile's global loads (complete during MFMA phase) ----
    if (k0 + 32 < D_MODEL) {
      const int kn = k0 + 32;
#pragma unroll
      for (int jj = 0; jj < 2; ++jj) {
        int idx = t + jj * 256, r = idx >> 3, kq = idx & 7;
        ra[jj] = *reinterpret_cast<const float4*>(&A[(size_t)(row0 + r) * D_MODEL + kn + kq * 4]);
      }
#pragma unroll
      for (int jj = 0; jj < 4; ++jj) {
        int idx = t + jj * 256, r = idx >> 3, kq = idx & 7;
        rw[jj] = *reinterpret_cast<const float4*>(&W[(size_t)(col0 + r) * D_MODEL + kn + kq * 4]);
      }
    }

    // ---- MFMA phase over current LDS tile ----
#pragma unroll
    for (int kk = 0; kk < 32; kk += 4) {
      const int kf = kk + (lane >> 4);
      double a0 = (double)As[wr +      (lane & 15)][kf];
      double a1 = (double)As[wr + 16 + (lane & 15)][kf];
      double b0 = (double)Ws[wc +      (lane & 15)][kf];
      double b1 = (double)Ws[wc + 16 + (lane & 15)][kf];
      double b2 = (double)Ws[wc + 32 + (lane & 15)][kf];
      double b3 = (double)Ws[wc + 48 + (lane & 15)][kf];
      acc[0][0] = __builtin_amdgcn_mfma_f64_16x16x4f64(a0, b0, acc[0][0], 0, 0, 0);
      acc[0][1] = __builtin_amdgcn_mfma_f64_16x16x4f64(a0, b1, acc[0][1], 0, 0, 0);
      acc[0][2] = __builtin_amdgcn_mfma_f64_16x16x4f64(a0, b2, acc[0][2], 0, 0, 0);
      acc[0][3] = __builtin_amdgcn_mfma_f64_16x16x4f64(a0, b3, acc[0][3], 0, 0, 0);
      acc[1][0] = __builtin_amdgcn_mfma_f64_16x16x4f64(a1, b0, acc[1][0], 0, 0, 0);
      acc[1][1] = __builtin_amdgcn_mfma_f64_16x16x4f64(a1, b1, acc[1][1], 0, 0, 0);
      acc[1][2] = __builtin_amdgcn_mfma_f64_16x16x4f64(a1, b2, acc[1][2], 0, 0, 0);
      acc[1][3] = __builtin_amdgcn_mfma_f64_16x16x4f64(a1, b3, acc[1][3], 0, 0, 0);
    }
    __syncthreads();
  }

  // ---- probe: verify D[6][5] (t=37, acc[0][0][1]) and D[13][3] (t=19, acc[0][0][3])
  if (t == 37) vals[0] = acc[0][0][1];
  if (t == 19) vals[1] = acc[0][0][3];
  {
    double p1 = 0, p2 = 0;
    const int kb = t * 4;
#pragma unroll
    for (int k = 0; k < 4; ++k) {
      p1 = fma((double)A[(size_t)(row0 + 6) * D_MODEL + kb + k],
               (double)W[(size_t)(col0 + 5) * D_MODEL + kb + k], p1);
      p2 = fma((double)A[(size_t)(row0 + 13) * D_MODEL + kb + k],
               (double)W[(size_t)(col0 + 3) * D_MODEL + kb + k], p2);
    }
    redbuf[t] = p1; redbuf[256 + t] = p2;
  }
  __syncthreads();
  for (int s = 128; s > 0; s >>= 1) {
    if (t < s) { redbuf[t] += redbuf[t + s]; redbuf[256 + t] += redbuf[256 + t + s]; }
    __syncthreads();
  }
  if (t == 0) {
    double r1 = redbuf[0], r2 = redbuf[256];
    bool ok = (fabs(r1 - vals[0]) <= 1e-9 * (fabs(r1) + 1.0)) &&
              (fabs(r2 - vals[1]) <= 1e-9 * (fabs(r2) + 1.0));
    okflag = ok ? 1 : 0;
  }
  __syncthreads();

  if (okflag) {
#pragma unroll
    for (int i = 0; i < 2; ++i)
#pragma unroll
      for (int j = 0; j < 4; ++j)
#pragma unroll
        for (int r = 0; r < 4; ++r) {
          int row = row0 + wr + i * 16 + (lane >> 4) + 4 * r;
          int col = col0 + wc + j * 16 + (lane & 15);
          double v = acc[i][j][r] + (double)bias[col];
          int b = row >> 11, tt = row & (T_SEQ - 1);
          int h = col >> 6, dk = col & 63;
          size_t oi = (((size_t)b * N_HEADS + h) * T_SEQ + tt) * D_HEAD + dk;
          out[oi] = v;
          if (kh) {
            _Float16 hh = (_Float16)(float)v;
            int cch = tt >> 7, klo = tt & 127;
            size_t off = (((size_t)(b * N_HEADS + h) * 16 + cch) << 14)
                       + (size_t)klo * 128 + (size_t)((dk * 2) ^ ((klo & 7) << 4));
            *reinterpret_cast<_Float16*>(kh + off) = hh;
          }
        }
  } else {
    // VALU fallback: 64x128 staged path (f32 stage, cvt on read — same values)
    const int ty = t >> 4, tx = t & 15;
    double vacc[4][8] = {{0.0}};
    for (int k0 = 0; k0 < D_MODEL; k0 += 32) {
#pragma unroll
      for (int jj = 0; jj < 2; ++jj) {
        int idx = t + jj * 256;
        int r = idx >> 3, kq = idx & 7;
        float4 va = *reinterpret_cast<const float4*>(&A[(size_t)(row0 + r) * D_MODEL + k0 + kq * 4]);
        As[r][kq*4+0] = va.x; As[r][kq*4+1] = va.y;
        As[r][kq*4+2] = va.z; As[r][kq*4+3] = va.w;
      }
#pragma unroll
      for (int jj = 0; jj < 4; ++jj) {
        int idx = t + jj * 256;
        int r = idx >> 3, kq = idx & 7;
        float4 vw = *reinterpret_cast<const float4*>(&W[(size_t)(col0 + r) * D_MODEL + k0 + kq * 4]);
        Ws[r][kq*4+0] = vw.x; Ws[r][kq*4+1] = vw.y;
        Ws[r][kq*4+2] = vw.z; Ws[r][kq*4+3] = vw.w;
      }
      __syncthreads();
#pragma unroll
      for (int kk = 0; kk < 32; ++kk) {
        double a[4], b[8];
#pragma unroll
        for (int i = 0; i < 4; ++i) a[i] = (double)As[ty + 16*i][kk];
#pragma unroll
        for (int j = 0; j < 8; ++j) b[j] = (double)Ws[tx + 16*j][kk];
#pragma unroll
        for (int i = 0; i < 4; ++i)
#pragma unroll
          for (int j = 0; j < 8; ++j) vacc[i][j] = fma(a[i], b[j], vacc[i][j]);
      }
      __syncthreads();
    }
#pragma unroll
    for (int i = 0; i < 4; ++i)
#pragma unroll
      for (int j = 0; j < 8; ++j) {
        int row = row0 + ty + 16*i, col = col0 + tx + 16*j;
        double v = vacc[i][j] + (double)bias[col];
        int b = row >> 11, tt = row & (T_SEQ - 1);
        int h = col >> 6, dk = col & 63;
        size_t oi = (((size_t)b * N_HEADS + h) * T_SEQ + tt) * D_HEAD + dk;
        out[oi] = v;
        if (kh) {
          _Float16 hh = (_Float16)(float)v;
          int cch = tt >> 7, klo = tt & 127;
          size_t off = (((size_t)(b * N_HEADS + h) * 16 + cch) << 14)
                     + (size_t)klo * 128 + (size_t)((dk * 2) ^ ((klo & 7) << 4));
          *reinterpret_cast<_Float16*>(kh + off) = hh;
        }
      }
  }
}

// ---------------------------------------------------------------------------
// Per-row tail with certified bands (round-16-proven).
// ---------------------------------------------------------------------------
__device__ __forceinline__ void process_row(
    const float (&s)[32], int* __restrict__ dkl, float* __restrict__ dwl,
    int* __restrict__ akl, float* __restrict__ awl,
    const double* __restrict__ qrow, const double* __restrict__ Kd,
    const float* __restrict__ V, unsigned mw,
    char* __restrict__ axh, char* __restrict__ axl,
    size_t axbase, int rsw, size_t kvbase, int lane)
{
  // fp32 64th-largest to 16384-ulp resolution (quant ~2e-3, folded into band)
  unsigned p = 0u;
  for (int bit = 31; bit >= 14; --bit) {
    unsigned cand = p | (1u << bit);
    float cf = key2f(cand);
    int cnt = 0;
#pragma unroll
    for (int j = 0; j < 32; ++j) cnt += (int)__popcll(__ballot(s[j] >= cf));
    if (cnt >= TOPK_N) p = cand;
  }
  const float pv = key2f(p);            // pv <= v32
  const float pn = key2f(p + 16384u);   // v32 < pn
  const float hi = pn + 2.f * EERR;     // s>=hi  => certainly in f64 top-64
  const float lo = pv - 2.f * EERR;     // s<lo   => certainly out

  // compact definite list (raw scores) and ambiguous list
  int m = 0, na = 0;
#pragma unroll
  for (int j = 0; j < 32; ++j) {
    float sv = s[j];
    bool isd = (sv >= hi);
    bool isa = (sv >= lo) && !isd;
    unsigned long long bd = __ballot(isd);
    unsigned long long ba = __ballot(isa);
    int k = j * 64 + lane;
    if (isd) {
      int pos = m + (int)__popcll(bd & ((1ull << lane) - 1ull));
      if (pos < DCAP) { dkl[pos] = k; dwl[pos] = sv; }
    }
    if (isa) {
      int pos = na + (int)__popcll(ba & ((1ull << lane) - 1ull));
      if (pos < ACAP) akl[pos] = k;
    }
    m += (int)__popcll(bd);
    na += (int)__popcll(ba);
  }
  if (m > DCAP) m = DCAP;   // unreachable: m <= 63
  if (na > ACAP) na = ACAP;
  const int need = TOPK_N - m;

  // deferred mask+laplace for definite list: one erf for all lanes
  {
    int kdef = dkl[lane];               // lane>=m reads stale LDS (safe)
    float sdef = dwl[lane];
    unsigned mwd = __shfl(mw, kdef & 63);
    bool mskd = ((mwd >> (kdef >> 6)) & 1u) != 0u;
    float wdef = mskd ? 0.f : 0.5f * (1.f + erff((sdef - LAP_MU_F) * LAP_INV_F));
    if (lane < m) dwl[lane] = wdef;
  }

  // lane-parallel f64 refine of ambiguous candidates (lane e owns akl[e])
  int ke = (na > 0) ? akl[lane < na ? lane : 0] : 0;
  const double* kr = &Kd[kvbase + (size_t)ke * D_HEAD];
  double a0 = 0, a1 = 0, a2 = 0, a3 = 0;
#pragma unroll
  for (int d = 0; d < 64; d += 4) {
    a0 = fma(qrow[d + 0], kr[d + 0], a0);
    a1 = fma(qrow[d + 1], kr[d + 1], a1);
    a2 = fma(qrow[d + 2], kr[d + 2], a2);
    a3 = fma(qrow[d + 3], kr[d + 3], a3);
  }
  double s64e = ((a0 + a1) + (a2 + a3)) * 0.125;

  // mask bit for own ambiguous candidate (cross-lane word fetch)
  unsigned mwk = __shfl(mw, ke & 63);
  bool mska = ((mwk >> (ke >> 6)) & 1u) != 0u;

  // rank among A by exact f64 (strict >): rank<need <=> s64 >= vk (ties kept)
  int rank = 0;
  for (int i = 0; i < na; ++i) {
    double vi = __shfl(s64e, i);
    rank += (vi > s64e) ? 1 : 0;
  }
  if (lane < na) {
    bool keep = (rank < need) && !mska;
    awl[lane] = keep ? 0.5f * (1.f + erff(((float)s64e - LAP_MU_F) * LAP_INV_F)) : 0.f;
  }

  // PV: lane owns output dim d=lane; 4 accumulators -> 4 outstanding loads
  float c0 = 0.f, c1 = 0.f, c2 = 0.f, c3 = 0.f;
  int e = 0;
  for (; e + 4 <= m; e += 4) {
    c0 = fmaf(dwl[e+0], V[kvbase + (size_t)dkl[e+0] * D_HEAD + lane], c0);
    c1 = fmaf(dwl[e+1], V[kvbase + (size_t)dkl[e+1] * D_HEAD + lane], c1);
    c2 = fmaf(dwl[e+2], V[kvbase + (size_t)dkl[e+2] * D_HEAD + lane], c2);
    c3 = fmaf(dwl[e+3], V[kvbase + (size_t)dkl[e+3] * D_HEAD + lane], c3);
  }
  for (; e < m; ++e)
    c0 = fmaf(dwl[e], V[kvbase + (size_t)dkl[e] * D_HEAD + lane], c0);
  for (int e2 = 0; e2 < na; ++e2)
    c1 = fmaf(awl[e2], V[kvbase + (size_t)akl[e2] * D_HEAD + lane], c1);

  float val = (c0 + c1) + (c2 + c3);
  _Float16 vh = (_Float16)val;
  _Float16 vl = (_Float16)(val - (float)vh);
  size_t off = axbase + (size_t)((lane * 2) ^ rsw);
  *reinterpret_cast<_Float16*>(axh + off) = vh;
  *reinterpret_cast<_Float16*>(axl + off) = vl;
}

// ---------------------------------------------------------------------------
// Fused attention (round-16/17/18-proven): direct-to-register K from the
// pre-swizzled image, 1-chunk prefetch, S_lds dbuf transpose, image output.
// ---------------------------------------------------------------------------
__global__ __launch_bounds__(512)
void attn_fused(const double* __restrict__ Qd, const double* __restrict__ Kd,
                const char* __restrict__ KhS, const float* __restrict__ V,
                const unsigned* __restrict__ mbits,
                char* __restrict__ AxH, char* __restrict__ AxL)
{
  __shared__ float    S_lds[2][128][17];  // 17 KB double-buffered transpose
  __shared__ char     pool[8192];         // QhL/QlL (prologue) | dk_l/dw_l (tail)
  __shared__ int      ak_l[QROWS][ACAP];  // 2.5 KB
  __shared__ float    aw_l[QROWS][ACAP];  // 2.5 KB

  _Float16 (*QhL)[64] = reinterpret_cast<_Float16(*)[64]>(pool);          // [16][64] 2KB
  _Float16 (*QlL)[64] = reinterpret_cast<_Float16(*)[64]>(pool + 2048);   // [16][64] 2KB
  int      (*dk_l)[DCAP] = reinterpret_cast<int(*)[DCAP]>(pool);          // [16][64] 4KB
  float    (*dw_l)[DCAP] = reinterpret_cast<float(*)[DCAP]>(pool + 4096); // [16][64] 4KB

  const int t = threadIdx.x, wv = t >> 6, lane = t & 63;
  const int bh = blockIdx.y, b = bh >> 4, h = bh & 15;
  const int q0 = blockIdx.x * QROWS;
  const size_t kvbase = (size_t)bh * T_SEQ * D_HEAD;
  const char* gbase = KhS + (((size_t)bh * 16) << 14);   // this bh's chunks

  // prologue: stage q rows (f16 hi/lo for MFMA B)
  for (int i = t; i < QROWS * 64; i += 512) {
    int r = i >> 6, d = i & 63;
    float qf = (float)Qd[kvbase + (size_t)(q0 + r) * D_HEAD + d];
    _Float16 hh = (_Float16)qf;
    QhL[r][d] = hh;
    QlL[r][d] = (_Float16)(qf - (float)hh);
  }
  __syncthreads();

  // hoist Q fragments: col=lane&15 (all 16 live), k=(lane>>4)*8+j
  const int qcol = lane & 15;
  const int kq = (lane >> 4) * 8;
  f16x8 Bh[2], Bl[2];
#pragma unroll
  for (int ds_ = 0; ds_ < 2; ++ds_) {
    Bh[ds_] = *reinterpret_cast<const f16x8*>(&QhL[qcol][ds_ * 32 + kq]);
    Bl[ds_] = *reinterpret_cast<const f16x8*>(&QlL[qcol][ds_ * 32 + kq]);
  }

  // per-lane K-image offsets within a chunk (wave's own 16 rows)
  const int rloc = wv * 16 + (lane & 15);
  const int off0 = rloc * 128 + ((0 * 64 + (lane >> 4) * 16) ^ ((rloc & 7) << 4));
  const int off1 = rloc * 128 + ((1 * 64 + (lane >> 4) * 16) ^ ((rloc & 7) << 4));

  const int r0 = wv * RPW;
  float s0[32], s1[32];

  // prefetch chunk 0
  f16x8 a0c = *reinterpret_cast<const f16x8*>(gbase + off0);
  f16x8 a1c = *reinterpret_cast<const f16x8*>(gbase + off1);

#pragma unroll
  for (int c = 0; c < 16; ++c) {
    const int cur = c & 1;
    // issue next chunk's loads (latency hides under MFMA + barrier)
    f16x8 a0n, a1n;
    if (c < 15) {
      const char* gc = gbase + ((size_t)(c + 1) << 14);
      a0n = *reinterpret_cast<const f16x8*>(gc + off0);
      a1n = *reinterpret_cast<const f16x8*>(gc + off1);
    }

    // MFMA: wave covers its 16 k-rows of chunk c
    f32x4 acc = {0.f, 0.f, 0.f, 0.f};
    acc = __builtin_amdgcn_mfma_f32_16x16x32_f16(a0c, Bh[0], acc, 0, 0, 0);
    acc = __builtin_amdgcn_mfma_f32_16x16x32_f16(a0c, Bl[0], acc, 0, 0, 0);
    acc = __builtin_amdgcn_mfma_f32_16x16x32_f16(a1c, Bh[1], acc, 0, 0, 0);
    acc = __builtin_amdgcn_mfma_f32_16x16x32_f16(a1c, Bl[1], acc, 0, 0, 0);

    // scatter D: row = k-local = wv*16 + (lane>>4)*4 + r2, col = q
#pragma unroll
    for (int r2 = 0; r2 < 4; ++r2)
      S_lds[cur][wv * 16 + (lane >> 4) * 4 + r2][qcol] = acc[r2];

    __syncthreads();   // orders scatter vs gather (dbuf parity protects reuse)

    // gather into selection layout: s[j] = score[k = j*64+lane]
    s0[c * 2 + 0] = S_lds[cur][lane][r0]          * 0.125f;
    s0[c * 2 + 1] = S_lds[cur][64 + lane][r0]     * 0.125f;
    s1[c * 2 + 0] = S_lds[cur][lane][r0 + 1]      * 0.125f;
    s1[c * 2 + 1] = S_lds[cur][64 + lane][r0 + 1] * 0.125f;

    a0c = a0n; a1c = a1n;
  }

  // wave-private tails (pool now reused as dk_l/dw_l — Q reads long done)
  {
    const int lr = r0, qg = q0 + lr;
    const size_t rowg = (size_t)b * T_SEQ + qg;
    unsigned mw = mbits[rowg * 64 + lane];
    int rb = (int)(rowg >> 6), rr = (int)(rowg & 63);
    size_t axbase = (((size_t)rb * 16 + h) << 13) + (size_t)rr * 128;
    process_row(s0, dk_l[lr], dw_l[lr], ak_l[lr], aw_l[lr],
                &Qd[kvbase + (size_t)qg * D_HEAD], Kd, V, mw,
                AxH, AxL, axbase, (rr & 7) << 4, kvbase, lane);
  }
  {
    const int lr = r0 + 1, qg = q0 + lr;
    const size_t rowg = (size_t)b * T_SEQ + qg;
    unsigned mw = mbits[rowg * 64 + lane];
    int rb = (int)(rowg >> 6), rr = (int)(rowg & 63);
    size_t axbase = (((size_t)rb * 16 + h) << 13) + (size_t)rr * 128;
    process_row(s1, dk_l[lr], dw_l[lr], ak_l[lr], aw_l[lr],
                &Qd[kvbase + (size_t)qg * D_HEAD], Kd, V, mw,
                AxH, AxL, axbase, (rr & 7) << 4, kvbase, lane);
  }
}

// ---------------------------------------------------------------------------
extern "C" void kernel_launch(void* const* d_in, const int* in_sizes, int n_in,
                              void* d_out, int out_size, void* d_ws, size_t ws_size,
                              hipStream_t stream)
{
  const float* query = (const float*)d_in[0];
  const float* key_  = (const float*)d_in[1];
  const float* value = (const float*)d_in[2];
  const int*   mask  = (const int*)d_in[3];
  const float* wq = (const float*)d_in[4];
  const float* bq = (const float*)d_in[5];
  const float* wk = (const float*)d_in[6];
  const float* bk = (const float*)d_in[7];
  const float* wvp = (const float*)d_in[8];
  const float* bv = (const float*)d_in[9];
  const float* wo = (const float*)d_in[10];
  const float* bo = (const float*)d_in[11];
  float* out = (float*)d_out;

  // ws regions (97 MB):
  //   [0,32M)   Qd f64     — transiently BvH/BvL images before Q-GEMM
  //   [32,64M)  Kd f64     — transiently AvH/AvL images; BoH/BoL after attn
  //   [64,72M)  KhS
  //   [80,96M)  AxH/AxL (attn output images, 8M each)
  //   [96,97M)  mbits
  double* Qd  = (double*)d_ws;
  double* Kd  = (double*)((char*)d_ws + ((size_t)32 << 20));
  char*   KhS = (char*)d_ws + ((size_t)64 << 20);
  char*   AxH = (char*)d_ws + ((size_t)80 << 20);
  char*   AxL = (char*)d_ws + ((size_t)88 << 20);
  unsigned* mbits = (unsigned*)((char*)d_ws + ((size_t)96 << 20));
  float*  Vb  = out;   // V-projection parks in d_out; final GEMM overwrites it

  char* BvH = (char*)d_ws;                                   // 2 MB  (wv hi)
  char* BvL = (char*)d_ws + ((size_t)2 << 20);               // 2 MB  (wv lo)
  char* AvH = (char*)d_ws + ((size_t)32 << 20);              // 8 MB  (value hi)
  char* AvL = (char*)d_ws + ((size_t)40 << 20);              // 8 MB  (value lo)
  char* BoH = (char*)d_ws + ((size_t)32 << 20);              // 2 MB  (wo hi, post-attn)
  char* BoL = (char*)d_ws + ((size_t)34 << 20);              // 2 MB  (wo lo)

  const int M = N_B * T_SEQ;   // 4096
  dim3 gg64(M / 64, D_MODEL / 64);

  // 1) V path first: its images live in the not-yet-written Qd/Kd regions
  hipLaunchKernelGGL(split16, dim3(1024 * 128 / 256), dim3(256), 0, stream, wvp, BvH, BvL, 64.f);
  hipLaunchKernelGGL(split16, dim3((size_t)M * 128 / 256), dim3(256), 0, stream, value, AvH, AvL, 1.f);
  hipLaunchKernelGGL(gemm_mfma_f16i, gg64, dim3(256), 0, stream, AvH, AvL, BvH, BvL,
                     bv, Vb, D_MODEL, 1);

  // 2) mask pack + merged f64 Q/K projection (self-verifying MFMA, pipelined)
  hipLaunchKernelGGL(pack_mask, dim3(M / 4), dim3(256), 0, stream, mask, mbits);
  dim3 gqk(M / 64, D_MODEL / 128, 2);
  hipLaunchKernelGGL(gemm_f64_qk, gqk, dim3(256), 0, stream,
                     query, key_, wq, wk, bq, bk, Qd, Kd, KhS);

  // 3) fused attention (writes AxH/AxL images directly)
  dim3 ga(T_SEQ / QROWS, N_B * N_HEADS);
  hipLaunchKernelGGL(attn_fused, ga, dim3(512), 0, stream, Qd, Kd, KhS, Vb, mbits, AxH, AxL);

  // 4) O path: wo images reuse Kd region (dead after attn)
  hipLaunchKernelGGL(split16, dim3(1024 * 128 / 256), dim3(256), 0, stream, wo, BoH, BoL, 64.f);
  hipLaunchKernelGGL(gemm_mfma_f16i, gg64, dim3(256), 0, stream, AxH, AxL, BoH, BoL,
                     bo, out, D_MODEL, 0);
}